// Round 12
// baseline (69.072 us; speedup 1.0000x reference)
//
#include <hip/hip_runtime.h>
#include <math.h>

// 2-layer GCN, scalar-per-node form, zero global atomics, 5 dispatches:
//   k_hist : per-chunk LDS histogram of bucket (dst>>8) -> bh[bucket][chunk]
//   k_bin  : per-block triangular prefix over bh (replaces colscan dispatch):
//            thread b sums bh[b][0..chunk) and the full row; block wave-scan of
//            totals -> buckbase (identical in all blocks; block 0 publishes);
//            then packed[base+pref+rank] = (src<<8)|(dst&255)
//   k_deg  : per bucket (256 nodes, 1024 thr) LDS int hist -> dinv, g
//   k_l1   : per bucket LDS float acc of g[src] -> u = dinv*h2(dinv*(acc+g))
//   k_l2   : per bucket LDS float acc of u[src] -> out = sigmoid(...)
// Lessons: r7 coop grid.sync ~110us/sync -> multi-kernel; r1/r2 global atomics
// 32B write-through -> zero-atomic; r10 chunk-local packed starves consumers
// -> keep packed bucket-contiguous; r12: colscan folded into bin (one less gap).

#define NBLK 256   // edge chunks; bh row length
#define TBE  512   // hist/bin threads
#define TBA  1024  // aggregation threads (16 waves)
#define MAXB 512   // max buckets (256 nodes each): n <= 131072

__device__ __forceinline__ int chunk_of(int blk) {
    // consecutive chunks -> same XCD (dispatch round-robins blk%8 across XCDs)
    return ((blk & 7) * (NBLK >> 3)) + (blk >> 3);
}

__global__ __launch_bounds__(TBE)
void k_hist(const int* __restrict__ dst, int* __restrict__ bh,
            int e, int ec, int nb) {
    __shared__ int sh[MAXB];
    const int t = threadIdx.x;
    const int chunk = chunk_of(blockIdx.x);
    for (int i = t; i < nb; i += TBE) sh[i] = 0;
    __syncthreads();
    int start = chunk * ec, end = min(e, start + ec);
    int tile = start;
    for (; tile + TBE * 4 <= end; tile += TBE * 4) {
        const int4 d4 = *reinterpret_cast<const int4*>(dst + tile + t * 4);
        atomicAdd(&sh[d4.x >> 8], 1);
        atomicAdd(&sh[d4.y >> 8], 1);
        atomicAdd(&sh[d4.z >> 8], 1);
        atomicAdd(&sh[d4.w >> 8], 1);
    }
    for (int i = tile + t; i < end; i += TBE) atomicAdd(&sh[dst[i] >> 8], 1);
    __syncthreads();
    for (int i = t; i < nb; i += TBE) bh[(size_t)i * NBLK + chunk] = sh[i];
}

__global__ __launch_bounds__(TBE)
void k_bin(const int* __restrict__ src, const int* __restrict__ dst,
           const int* __restrict__ bh, int* __restrict__ buckbase,
           int* __restrict__ packed, int e, int ec, int nb) {
    __shared__ int scur[MAXB];    // bucket write cursors
    __shared__ int spref[MAXB];   // my-chunk prefix per bucket
    __shared__ int wtot[TBE / 64];
    const int t = threadIdx.x;
    const int lane = t & 63, wid = t >> 6;
    const int chunk = chunk_of(blockIdx.x);

    // --- per-bucket row walk: pref = sum bh[b][0..chunk), tot = full row sum ---
    int tot = 0, pref = 0;
    if (t < nb) {
        const int* row = bh + (size_t)t * NBLK;
        int c = 0;
        for (; c + 4 <= chunk; c += 4) {
            int4 v = *reinterpret_cast<const int4*>(row + c);
            pref += v.x + v.y + v.z + v.w;
        }
        for (; c < chunk; ++c) pref += row[c];
        tot = pref;
        for (; (c & 3) && c < NBLK; ++c) tot += row[c];   // realign to 16B
        for (; c + 4 <= NBLK; c += 4) {
            int4 v = *reinterpret_cast<const int4*>(row + c);
            tot += v.x + v.y + v.z + v.w;
        }
        spref[t] = pref;
    }

    // --- block-wide exclusive scan of totals -> bucket bases ---
    int winc = tot;
#pragma unroll
    for (int off = 1; off < 64; off <<= 1) {
        int w = __shfl_up(winc, off, 64);
        if (lane >= off) winc += w;
    }
    if (lane == 63) wtot[wid] = winc;
    __syncthreads();
    int wbase = 0;
#pragma unroll
    for (int w = 0; w < TBE / 64; ++w) wbase += (w < wid) ? wtot[w] : 0;
    int ex = wbase + winc - tot;
    if (t < nb) {
        if (blockIdx.x == 0) buckbase[t] = ex;   // publish for deg/l1/l2
        scur[t] = ex + spref[t];                 // this chunk's write cursor
    }
    if (blockIdx.x == 0 && t == 0) buckbase[nb] = e;
    __syncthreads();

    // --- scatter this chunk's edges into bucket-contiguous packed[] ---
    int start = chunk * ec, end = min(e, start + ec);
    int tile = start;
    for (; tile + TBE * 4 <= end; tile += TBE * 4) {
        const int4 s4 = *reinterpret_cast<const int4*>(src + tile + t * 4);
        const int4 d4 = *reinterpret_cast<const int4*>(dst + tile + t * 4);
        int p;
        p = atomicAdd(&scur[d4.x >> 8], 1); packed[p] = (s4.x << 8) | (d4.x & 255);
        p = atomicAdd(&scur[d4.y >> 8], 1); packed[p] = (s4.y << 8) | (d4.y & 255);
        p = atomicAdd(&scur[d4.z >> 8], 1); packed[p] = (s4.z << 8) | (d4.z & 255);
        p = atomicAdd(&scur[d4.w >> 8], 1); packed[p] = (s4.w << 8) | (d4.w & 255);
    }
    for (int i = tile + t; i < end; i += TBE) {
        int d = dst[i], s = src[i];
        int p = atomicAdd(&scur[d >> 8], 1);
        packed[p] = (s << 8) | (d & 255);
    }
}

// Vectorized segment walk: scalar head to 16B alignment, int4 body, scalar tail.
#define SEG_WALK(S0, S1, BODY_PK)                                        \
    {                                                                    \
        int head = min((S1), ((S0) + 3) & ~3);                           \
        for (int j = (S0) + t; j < head; j += TBA) {                     \
            int pk = packed[j]; BODY_PK;                                 \
        }                                                                \
        int nvec = ((S1) - head) >> 2;                                   \
        const int4* pv = reinterpret_cast<const int4*>(packed + head);   \
        for (int j = t; j < nvec; j += TBA) {                            \
            int4 q = pv[j];                                              \
            { int pk = q.x; BODY_PK; }                                   \
            { int pk = q.y; BODY_PK; }                                   \
            { int pk = q.z; BODY_PK; }                                   \
            { int pk = q.w; BODY_PK; }                                   \
        }                                                                \
        for (int j = head + 4 * nvec + t; j < (S1); j += TBA) {          \
            int pk = packed[j]; BODY_PK;                                 \
        }                                                                \
    }

__global__ __launch_bounds__(TBA)
void k_deg(const int* __restrict__ packed, const int* __restrict__ buckbase,
           const float* __restrict__ x, float* __restrict__ dinv,
           float* __restrict__ g, int n) {
    __shared__ int cnt[1024];      // 256 nodes x 4 banks
    const int t = threadIdx.x, b = blockIdx.x;
    cnt[t] = 0;
    __syncthreads();
    const int bank = (t & 3) << 8;
    int s0 = buckbase[b], s1 = buckbase[b + 1];
    SEG_WALK(s0, s1, atomicAdd(&cnt[bank | (pk & 255)], 1))
    __syncthreads();
    if (t < 256) {
        int node = (b << 8) + t;
        if (node < n) {
            int c = cnt[t] + cnt[256 + t] + cnt[512 + t] + cnt[768 + t];
            float di = rsqrtf(1.0f + (float)c);
            dinv[node] = di;
            g[node] = di * x[node];
        }
    }
}

__global__ __launch_bounds__(TBA)
void k_l1(const int* __restrict__ packed, const int* __restrict__ buckbase,
          const float* __restrict__ g, const float* __restrict__ dinv,
          const float* __restrict__ W1, const float* __restrict__ b1,
          const float* __restrict__ W2, float* __restrict__ u, int n, int K) {
    __shared__ float acc[1024];    // 256 nodes x 4 banks
    const int t = threadIdx.x, b = blockIdx.x;
    acc[t] = 0.f;
    __syncthreads();
    const int bank = (t & 3) << 8;
    int s0 = buckbase[b], s1 = buckbase[b + 1];
    SEG_WALK(s0, s1, atomicAdd(&acc[bank | (pk & 255)], g[pk >> 8]))
    __syncthreads();
    if (t < 256) {
        int node = (b << 8) + t;
        if (node < n) {
            float s = acc[t] + acc[256 + t] + acc[512 + t] + acc[768 + t];
            float di = dinv[node];
            float tt = di * (s + g[node]);
            float h2 = 0.f;
            for (int k = 0; k < K; ++k) {
                float z = fmaf(W1[k], tt, b1[k]);
                h2 = fmaf(__fdividef(1.f, 1.f + __expf(-z)), W2[k], h2);
            }
            u[node] = di * h2;
        }
    }
}

__global__ __launch_bounds__(TBA)
void k_l2(const int* __restrict__ packed, const int* __restrict__ buckbase,
          const float* __restrict__ u, const float* __restrict__ dinv,
          const float* __restrict__ b2, float* __restrict__ out, int n) {
    __shared__ float acc[1024];
    const int t = threadIdx.x, b = blockIdx.x;
    acc[t] = 0.f;
    __syncthreads();
    const int bank = (t & 3) << 8;
    int s0 = buckbase[b], s1 = buckbase[b + 1];
    SEG_WALK(s0, s1, atomicAdd(&acc[bank | (pk & 255)], u[pk >> 8]))
    __syncthreads();
    if (t < 256) {
        int node = (b << 8) + t;
        if (node < n) {
            float s = acc[t] + acc[256 + t] + acc[512 + t] + acc[768 + t];
            float z = fmaf(dinv[node], s + u[node], b2[0]);
            out[node] = __fdividef(1.f, 1.f + __expf(-z));
        }
    }
}

// ---------------- fallback (round-1 atomic path, 3n floats) ----------------
__global__ void f_init(float* __restrict__ deg, int n) {
    int i = blockIdx.x * 256 + threadIdx.x;
    if (i < n) deg[i] = 1.0f;
}
__global__ void f_degree(const int* __restrict__ dst, float* __restrict__ deg, int e) {
    int i = blockIdx.x * 256 + threadIdx.x;
    if (i < e) atomicAdd(&deg[dst[i]], 1.0f);
}
__global__ void f_node1(const float* __restrict__ x, float* dd,
                        float* __restrict__ g, float* __restrict__ s, int n) {
    int i = blockIdx.x * 256 + threadIdx.x;
    if (i < n) {
        float di = rsqrtf(dd[i]);
        dd[i] = di;
        float gi = di * x[i];
        g[i] = gi; s[i] = gi;
    }
}
__global__ void f_scatter(const int* __restrict__ src, const int* __restrict__ dst,
                          const float* __restrict__ g, float* __restrict__ s, int e) {
    int i = blockIdx.x * 256 + threadIdx.x;
    if (i < e) atomicAdd(&s[dst[i]], g[src[i]]);
}
__global__ void f_node2(const float* __restrict__ dinv, const float* s,
                        const float* __restrict__ W1, const float* __restrict__ b1,
                        const float* __restrict__ W2, float* u, float* r, int n, int K) {
    int i = blockIdx.x * 256 + threadIdx.x;
    if (i < n) {
        float tt = dinv[i] * s[i];
        float h2 = 0.f;
        for (int k = 0; k < K; ++k) {
            float z = fmaf(W1[k], tt, b1[k]);
            h2 = fmaf(__fdividef(1.f, 1.f + __expf(-z)), W2[k], h2);
        }
        float ui = dinv[i] * h2;
        u[i] = ui; r[i] = ui;
    }
}
__global__ void f_out(const float* __restrict__ dinv, const float* __restrict__ r,
                      const float* __restrict__ b2, float* __restrict__ out, int n) {
    int i = blockIdx.x * 256 + threadIdx.x;
    if (i < n) {
        float z = fmaf(dinv[i], r[i], b2[0]);
        out[i] = __fdividef(1.f, 1.f + __expf(-z));
    }
}

extern "C" void kernel_launch(void* const* d_in, const int* in_sizes, int n_in,
                              void* d_out, int out_size, void* d_ws, size_t ws_size,
                              hipStream_t stream) {
    const float* x  = (const float*)d_in[0];
    const int*   ei = (const int*)d_in[1];
    const float* W1 = (const float*)d_in[2];
    const float* b1 = (const float*)d_in[3];
    const float* W2 = (const float*)d_in[4];
    const float* b2 = (const float*)d_in[5];

    const int n = in_sizes[0];
    const int e = in_sizes[1] / 2;
    const int K = in_sizes[2];
    const int* src = ei;
    const int* dst = ei + e;
    float* out = (float*)d_out;

    const int nb = (n + 255) >> 8;                     // buckets (256 nodes)
    const int ec = (((e + NBLK - 1) / NBLK) + 3) & ~3; // edges/chunk, mult of 4

    // ws: bh[nb*NBLK] buckbase[nb+1] packed[e] dinv[n] g[n] u[n]
    size_t need = ((size_t)nb * NBLK + (size_t)nb + 1 + (size_t)e + 3 * (size_t)n) * 4;

    if (nb <= MAXB && n < (1 << 23) && (e & 3) == 0 && ws_size >= need) {
        int* bh       = (int*)d_ws;
        int* buckbase = bh + (size_t)nb * NBLK;
        int* packed   = buckbase + nb + 1;
        float* dinv   = (float*)(packed + e);
        float* g      = dinv + n;
        float* u      = g + n;

        k_hist<<<NBLK, TBE, 0, stream>>>(dst, bh, e, ec, nb);
        k_bin <<<NBLK, TBE, 0, stream>>>(src, dst, bh, buckbase, packed, e, ec, nb);
        k_deg <<<nb, TBA, 0, stream>>>(packed, buckbase, x, dinv, g, n);
        k_l1  <<<nb, TBA, 0, stream>>>(packed, buckbase, g, dinv, W1, b1, W2, u, n, K);
        k_l2  <<<nb, TBA, 0, stream>>>(packed, buckbase, u, dinv, b2, out, n);
    } else {
        float* A = (float*)d_ws;
        float* B = A + n;
        float* C = B + n;
        const int bn = (n + 255) / 256;
        const int be = (e + 255) / 256;
        f_init   <<<bn, 256, 0, stream>>>(A, n);
        f_degree <<<be, 256, 0, stream>>>(dst, A, e);
        f_node1  <<<bn, 256, 0, stream>>>(x, A, B, C, n);
        f_scatter<<<be, 256, 0, stream>>>(src, dst, B, C, e);
        f_node2  <<<bn, 256, 0, stream>>>(A, C, W1, b1, W2, B, C, n, K);
        f_scatter<<<be, 256, 0, stream>>>(src, dst, B, C, e);
        f_out    <<<bn, 256, 0, stream>>>(A, C, b2, out, n);
    }
}

// Round 13
// 57.452 us; speedup vs baseline: 1.2023x; 1.2023x over previous
//
#include <hip/hip_runtime.h>
#include <math.h>

// 2-layer GCN, scalar-per-node form, zero global atomics, 6 dispatches:
//   k_hist   : per-chunk LDS histogram of bucket (dst>>8) -> bh[bucket][chunk]
//   k_colscan: one wave per bucket row (int4 + shfl_up) -> bh ranks, bucktot
//   k_bin    : inline wave-scan of bucktot; packed[base+rank]=(src<<8)|(dst&255)
//   k_deg    : per bucket (256 nodes, 1024 thr) LDS int hist -> dinv, g
//   k_l1     : per bucket LDS float acc of g[src] -> u = dinv*h2(dinv*(acc+g))
//   k_l2     : per bucket LDS float acc of u[src] -> out = sigmoid(...)
// Lessons: r7 coop grid.sync ~110us/sync -> multi-kernel; r1/r2 global atomics
// 32B write-through -> zero-atomic; r10 chunk-local packed starves consumer
// lanes -> keep packed globally bucket-contiguous (3 consumers, 1 producer);
// r12 folding colscan into bin adds a serial per-thread row walk -> keep the
// separate wave-parallel colscan. This is the measured optimum (57.6us).

#define NBLK 256   // edge chunks; bh row length
#define TBE  512   // hist/bin threads (8 waves/CU at 1 block/CU)
#define TBC  256   // colscan threads
#define TBA  1024  // aggregation threads (16 waves)
#define MAXB 512   // max buckets (256 nodes each): n <= 131072

__device__ __forceinline__ int chunk_of(int blk) {
    // consecutive chunks -> same XCD (dispatch round-robins blk%8 across XCDs)
    return ((blk & 7) * (NBLK >> 3)) + (blk >> 3);
}

__global__ __launch_bounds__(TBE)
void k_hist(const int* __restrict__ dst, int* __restrict__ bh,
            int e, int ec, int nb) {
    __shared__ int sh[MAXB];
    const int t = threadIdx.x;
    const int chunk = chunk_of(blockIdx.x);
    for (int i = t; i < nb; i += TBE) sh[i] = 0;
    __syncthreads();
    int start = chunk * ec, end = min(e, start + ec);
    int tile = start;
    for (; tile + TBE * 4 <= end; tile += TBE * 4) {
        const int4 d4 = *reinterpret_cast<const int4*>(dst + tile + t * 4);
        atomicAdd(&sh[d4.x >> 8], 1);
        atomicAdd(&sh[d4.y >> 8], 1);
        atomicAdd(&sh[d4.z >> 8], 1);
        atomicAdd(&sh[d4.w >> 8], 1);
    }
    for (int i = tile + t; i < end; i += TBE) atomicAdd(&sh[dst[i] >> 8], 1);
    __syncthreads();
    for (int i = t; i < nb; i += TBE) bh[(size_t)i * NBLK + chunk] = sh[i];
}

// One wave per bucket row (256 ints): lane owns one int4; lane-local prefix +
// shfl_up wave scan; coalesced row access.
__global__ __launch_bounds__(TBC)
void k_colscan(int* __restrict__ bh, int* __restrict__ bucktot, int nb) {
    const int lane = threadIdx.x & 63;
    const int wid = threadIdx.x >> 6;
    const int b = blockIdx.x * 4 + wid;
    if (b >= nb) return;
    int4* row = reinterpret_cast<int4*>(bh + (size_t)b * NBLK + lane * 4);
    int4 v0 = row[0];
    int s = v0.x + v0.y + v0.z + v0.w;
    int inc = s;
#pragma unroll
    for (int off = 1; off < 64; off <<= 1) {
        int w = __shfl_up(inc, off, 64);
        if (lane >= off) inc += w;
    }
    int run = inc - s;  // wave-exclusive base for this lane
    int c;
    c = v0.x; v0.x = run; run += c;  c = v0.y; v0.y = run; run += c;
    c = v0.z; v0.z = run; run += c;  c = v0.w; v0.w = run; run += c;
    row[0] = v0;
    if (lane == 63) bucktot[b] = inc;
}

__global__ __launch_bounds__(TBE)
void k_bin(const int* __restrict__ src, const int* __restrict__ dst,
           const int* __restrict__ bh, const int* __restrict__ bucktot,
           int* __restrict__ buckbase, int* __restrict__ packed,
           int e, int ec, int nb) {
    __shared__ int sbase[MAXB];   // exclusive bucket bases -> then write cursors
    __shared__ int wtot[TBE / 64];
    const int t = threadIdx.x;
    const int lane = t & 63, wid = t >> 6;
    const int chunk = chunk_of(blockIdx.x);

    // inline exclusive scan of bucktot: wave-scan + 8-wave combine (2 barriers)
    int i0 = 2 * t, i1 = 2 * t + 1;
    int c0 = (i0 < nb) ? bucktot[i0] : 0;
    int c1 = (i1 < nb) ? bucktot[i1] : 0;
    int tsum = c0 + c1;
    int winc = tsum;
#pragma unroll
    for (int off = 1; off < 64; off <<= 1) {
        int w = __shfl_up(winc, off, 64);
        if (lane >= off) winc += w;
    }
    if (lane == 63) wtot[wid] = winc;
    __syncthreads();
    int wbase = 0;
#pragma unroll
    for (int w = 0; w < TBE / 64; ++w) wbase += (w < wid) ? wtot[w] : 0;
    int ex = wbase + winc - tsum;
    if (i0 < nb) sbase[i0] = ex;
    if (i1 < nb) sbase[i1] = ex + c0;
    __syncthreads();

    if (blockIdx.x == 0) {   // publish buckbase for deg/l1/l2
        for (int i = t; i < nb; i += TBE) buckbase[i] = sbase[i];
        if (t == 0) buckbase[nb] = e;
    }
    // convert to this chunk's write cursors (same thread per slot, no race)
    for (int i = t; i < nb; i += TBE) sbase[i] += bh[(size_t)i * NBLK + chunk];
    __syncthreads();

    int start = chunk * ec, end = min(e, start + ec);
    int tile = start;
    for (; tile + TBE * 4 <= end; tile += TBE * 4) {
        const int4 s4 = *reinterpret_cast<const int4*>(src + tile + t * 4);
        const int4 d4 = *reinterpret_cast<const int4*>(dst + tile + t * 4);
        int p;
        p = atomicAdd(&sbase[d4.x >> 8], 1); packed[p] = (s4.x << 8) | (d4.x & 255);
        p = atomicAdd(&sbase[d4.y >> 8], 1); packed[p] = (s4.y << 8) | (d4.y & 255);
        p = atomicAdd(&sbase[d4.z >> 8], 1); packed[p] = (s4.z << 8) | (d4.z & 255);
        p = atomicAdd(&sbase[d4.w >> 8], 1); packed[p] = (s4.w << 8) | (d4.w & 255);
    }
    for (int i = tile + t; i < end; i += TBE) {
        int d = dst[i], s = src[i];
        int p = atomicAdd(&sbase[d >> 8], 1);
        packed[p] = (s << 8) | (d & 255);
    }
}

// Vectorized segment walk: scalar head to 16B alignment, int4 body, scalar tail.
#define SEG_WALK(S0, S1, BODY_PK)                                        \
    {                                                                    \
        int head = min((S1), ((S0) + 3) & ~3);                           \
        for (int j = (S0) + t; j < head; j += TBA) {                     \
            int pk = packed[j]; BODY_PK;                                 \
        }                                                                \
        int nvec = ((S1) - head) >> 2;                                   \
        const int4* pv = reinterpret_cast<const int4*>(packed + head);   \
        for (int j = t; j < nvec; j += TBA) {                            \
            int4 q = pv[j];                                              \
            { int pk = q.x; BODY_PK; }                                   \
            { int pk = q.y; BODY_PK; }                                   \
            { int pk = q.z; BODY_PK; }                                   \
            { int pk = q.w; BODY_PK; }                                   \
        }                                                                \
        for (int j = head + 4 * nvec + t; j < (S1); j += TBA) {          \
            int pk = packed[j]; BODY_PK;                                 \
        }                                                                \
    }

__global__ __launch_bounds__(TBA)
void k_deg(const int* __restrict__ packed, const int* __restrict__ buckbase,
           const float* __restrict__ x, float* __restrict__ dinv,
           float* __restrict__ g, int n) {
    __shared__ int cnt[1024];      // 256 nodes x 4 banks
    const int t = threadIdx.x, b = blockIdx.x;
    cnt[t] = 0;
    __syncthreads();
    const int bank = (t & 3) << 8;
    int s0 = buckbase[b], s1 = buckbase[b + 1];
    SEG_WALK(s0, s1, atomicAdd(&cnt[bank | (pk & 255)], 1))
    __syncthreads();
    if (t < 256) {
        int node = (b << 8) + t;
        if (node < n) {
            int c = cnt[t] + cnt[256 + t] + cnt[512 + t] + cnt[768 + t];
            float di = rsqrtf(1.0f + (float)c);
            dinv[node] = di;
            g[node] = di * x[node];
        }
    }
}

__global__ __launch_bounds__(TBA)
void k_l1(const int* __restrict__ packed, const int* __restrict__ buckbase,
          const float* __restrict__ g, const float* __restrict__ dinv,
          const float* __restrict__ W1, const float* __restrict__ b1,
          const float* __restrict__ W2, float* __restrict__ u, int n, int K) {
    __shared__ float acc[1024];    // 256 nodes x 4 banks
    const int t = threadIdx.x, b = blockIdx.x;
    acc[t] = 0.f;
    __syncthreads();
    const int bank = (t & 3) << 8;
    int s0 = buckbase[b], s1 = buckbase[b + 1];
    SEG_WALK(s0, s1, atomicAdd(&acc[bank | (pk & 255)], g[pk >> 8]))
    __syncthreads();
    if (t < 256) {
        int node = (b << 8) + t;
        if (node < n) {
            float s = acc[t] + acc[256 + t] + acc[512 + t] + acc[768 + t];
            float di = dinv[node];
            float tt = di * (s + g[node]);
            float h2 = 0.f;
            for (int k = 0; k < K; ++k) {
                float z = fmaf(W1[k], tt, b1[k]);
                h2 = fmaf(__fdividef(1.f, 1.f + __expf(-z)), W2[k], h2);
            }
            u[node] = di * h2;
        }
    }
}

__global__ __launch_bounds__(TBA)
void k_l2(const int* __restrict__ packed, const int* __restrict__ buckbase,
          const float* __restrict__ u, const float* __restrict__ dinv,
          const float* __restrict__ b2, float* __restrict__ out, int n) {
    __shared__ float acc[1024];
    const int t = threadIdx.x, b = blockIdx.x;
    acc[t] = 0.f;
    __syncthreads();
    const int bank = (t & 3) << 8;
    int s0 = buckbase[b], s1 = buckbase[b + 1];
    SEG_WALK(s0, s1, atomicAdd(&acc[bank | (pk & 255)], u[pk >> 8]))
    __syncthreads();
    if (t < 256) {
        int node = (b << 8) + t;
        if (node < n) {
            float s = acc[t] + acc[256 + t] + acc[512 + t] + acc[768 + t];
            float z = fmaf(dinv[node], s + u[node], b2[0]);
            out[node] = __fdividef(1.f, 1.f + __expf(-z));
        }
    }
}

// ---------------- fallback (round-1 atomic path, 3n floats) ----------------
__global__ void f_init(float* __restrict__ deg, int n) {
    int i = blockIdx.x * 256 + threadIdx.x;
    if (i < n) deg[i] = 1.0f;
}
__global__ void f_degree(const int* __restrict__ dst, float* __restrict__ deg, int e) {
    int i = blockIdx.x * 256 + threadIdx.x;
    if (i < e) atomicAdd(&deg[dst[i]], 1.0f);
}
__global__ void f_node1(const float* __restrict__ x, float* dd,
                        float* __restrict__ g, float* __restrict__ s, int n) {
    int i = blockIdx.x * 256 + threadIdx.x;
    if (i < n) {
        float di = rsqrtf(dd[i]);
        dd[i] = di;
        float gi = di * x[i];
        g[i] = gi; s[i] = gi;
    }
}
__global__ void f_scatter(const int* __restrict__ src, const int* __restrict__ dst,
                          const float* __restrict__ g, float* __restrict__ s, int e) {
    int i = blockIdx.x * 256 + threadIdx.x;
    if (i < e) atomicAdd(&s[dst[i]], g[src[i]]);
}
__global__ void f_node2(const float* __restrict__ dinv, const float* s,
                        const float* __restrict__ W1, const float* __restrict__ b1,
                        const float* __restrict__ W2, float* u, float* r, int n, int K) {
    int i = blockIdx.x * 256 + threadIdx.x;
    if (i < n) {
        float tt = dinv[i] * s[i];
        float h2 = 0.f;
        for (int k = 0; k < K; ++k) {
            float z = fmaf(W1[k], tt, b1[k]);
            h2 = fmaf(__fdividef(1.f, 1.f + __expf(-z)), W2[k], h2);
        }
        float ui = dinv[i] * h2;
        u[i] = ui; r[i] = ui;
    }
}
__global__ void f_out(const float* __restrict__ dinv, const float* __restrict__ r,
                      const float* __restrict__ b2, float* __restrict__ out, int n) {
    int i = blockIdx.x * 256 + threadIdx.x;
    if (i < n) {
        float z = fmaf(dinv[i], r[i], b2[0]);
        out[i] = __fdividef(1.f, 1.f + __expf(-z));
    }
}

extern "C" void kernel_launch(void* const* d_in, const int* in_sizes, int n_in,
                              void* d_out, int out_size, void* d_ws, size_t ws_size,
                              hipStream_t stream) {
    const float* x  = (const float*)d_in[0];
    const int*   ei = (const int*)d_in[1];
    const float* W1 = (const float*)d_in[2];
    const float* b1 = (const float*)d_in[3];
    const float* W2 = (const float*)d_in[4];
    const float* b2 = (const float*)d_in[5];

    const int n = in_sizes[0];
    const int e = in_sizes[1] / 2;
    const int K = in_sizes[2];
    const int* src = ei;
    const int* dst = ei + e;
    float* out = (float*)d_out;

    const int nb = (n + 255) >> 8;                     // buckets (256 nodes)
    const int ec = (((e + NBLK - 1) / NBLK) + 3) & ~3; // edges/chunk, mult of 4

    // ws: bh[nb*NBLK] bucktot[nb] buckbase[nb+1] packed[e] dinv[n] g[n] u[n]
    size_t need = ((size_t)nb * NBLK + 2 * (size_t)nb + 1 + (size_t)e + 3 * (size_t)n) * 4;

    if (nb <= MAXB && n < (1 << 23) && (e & 3) == 0 && ws_size >= need) {
        int* bh       = (int*)d_ws;
        int* bucktot  = bh + (size_t)nb * NBLK;
        int* buckbase = bucktot + nb;
        int* packed   = buckbase + nb + 1;
        float* dinv   = (float*)(packed + e);
        float* g      = dinv + n;
        float* u      = g + n;

        k_hist   <<<NBLK, TBE, 0, stream>>>(dst, bh, e, ec, nb);
        k_colscan<<<(nb + 3) / 4, TBC, 0, stream>>>(bh, bucktot, nb);
        k_bin    <<<NBLK, TBE, 0, stream>>>(src, dst, bh, bucktot, buckbase,
                                            packed, e, ec, nb);
        k_deg    <<<nb, TBA, 0, stream>>>(packed, buckbase, x, dinv, g, n);
        k_l1     <<<nb, TBA, 0, stream>>>(packed, buckbase, g, dinv, W1, b1, W2, u, n, K);
        k_l2     <<<nb, TBA, 0, stream>>>(packed, buckbase, u, dinv, b2, out, n);
    } else {
        float* A = (float*)d_ws;
        float* B = A + n;
        float* C = B + n;
        const int bn = (n + 255) / 256;
        const int be = (e + 255) / 256;
        f_init   <<<bn, 256, 0, stream>>>(A, n);
        f_degree <<<be, 256, 0, stream>>>(dst, A, e);
        f_node1  <<<bn, 256, 0, stream>>>(x, A, B, C, n);
        f_scatter<<<be, 256, 0, stream>>>(src, dst, B, C, e);
        f_node2  <<<bn, 256, 0, stream>>>(A, C, W1, b1, W2, B, C, n, K);
        f_scatter<<<be, 256, 0, stream>>>(src, dst, B, C, e);
        f_out    <<<bn, 256, 0, stream>>>(A, C, b2, out, n);
    }
}